// Round 6
// baseline (97.280 us; speedup 1.0000x reference)
//
#include <hip/hip_runtime.h>
#include <hip/hip_bf16.h>

#define MASK_ID 50264
#define Bn 16
#define Sn 2048
#define Hn 1024
#define Ln 128

typedef __attribute__((ext_vector_type(8))) short short8;
typedef __attribute__((ext_vector_type(4))) float f32x4;

__device__ __forceinline__ unsigned short f2bf(float f) {
    __hip_bfloat16 h = __float2bfloat16(f);
    return __builtin_bit_cast(unsigned short, h);
}
__device__ __forceinline__ void gload16(const void* g, void* l) {
    __builtin_amdgcn_global_load_lds((const __attribute__((address_space(1))) void*)g,
                                     (__attribute__((address_space(3))) void*)l, 16, 0, 0);
}
__device__ __forceinline__ void st_agent(float* p, float v) {
    __hip_atomic_store(p, v, __ATOMIC_RELAXED, __HIP_MEMORY_SCOPE_AGENT);
}
__device__ __forceinline__ float ld_agent(const float* p) {
    return __hip_atomic_load(p, __ATOMIC_RELAXED, __HIP_MEMORY_SCOPE_AGENT);
}
// read 8 f32 (two XOR-swizzled 16B chunks) from LDS row, convert to bf16 short8
__device__ __forceinline__ short8 ld_cvt(const char* rowbase, int s, int kgrp) {
    f32x4 lo = *(const f32x4*)(rowbase + (((kgrp * 2)     ^ s) << 4));
    f32x4 hi = *(const f32x4*)(rowbase + (((kgrp * 2 + 1) ^ s) << 4));
    short8 r;
    r[0] = (short)f2bf(lo[0]); r[1] = (short)f2bf(lo[1]);
    r[2] = (short)f2bf(lo[2]); r[3] = (short)f2bf(lo[3]);
    r[4] = (short)f2bf(hi[0]); r[5] = (short)f2bf(hi[1]);
    r[6] = (short)f2bf(hi[2]); r[7] = (short)f2bf(hi[3]);
    return r;
}

// ONE kernel, ONE graph node. 512 blocks (16 by x 32 bx), 256 threads (4 waves).
// f32 staged async via global_load_lds (pre-swizzled global source, linear LDS dest),
// f32->bf16 on fragment read, MFMA, fused x via broadcast-q MFMA (waves 2,3),
// per-tile partials -> last-block finalize (mod-512 done counter, no reset needed).
__global__ __launch_bounds__(256, 2) void fused2_k(
        const int* __restrict__ ids, const float* __restrict__ q,
        const float* __restrict__ seq, const int* __restrict__ offsets,
        const float* __restrict__ W, const float* __restrict__ bias,
        const int* __restrict__ labels, const int* __restrict__ events,
        float* __restrict__ yn2p, float* __restrict__ dotp, float* __restrict__ xn2p,
        unsigned int* __restrict__ done, float* __restrict__ out)
{
    __shared__ float As[2][4096];            // 2 x 16KB : [128 rows][32 f32], 16B-chunk XOR swz
    __shared__ float Bs[2][1024];            // 2 x 4KB  : [32 rows][32 f32], same swz
    __shared__ unsigned short qs[1024];      // 2KB bf16, linear
    __shared__ int   offs[128];
    __shared__ int   t4[4];
    __shared__ float xvs[32], xred[2];
    __shared__ float red[128][2];
    __shared__ int   lastf;
    __shared__ float xns[16], numL[16], denL[16], ln16[16];

    const int blk = blockIdx.x, tid = threadIdx.x;
    const int wv = tid >> 6, l = tid & 63;
    // XCD partition: XCD x gets 4 by x 16 bx (L2-friendly)
    const int x = blk & 7, ib = blk >> 3;
    const int by = (x >> 1) * 4 + (ib >> 4);
    const int bx = (x & 1) * 16 + (ib & 15);
    const int rbase = by * 128, cbase = bx * 32;
    const int l15 = l & 15, kgrp = l >> 4;

    if (tid < 128) offs[tid] = offsets[tid];

    // ---- maskpos for this block's batch ----
    int lm = Sn;
    const int* idrow = ids + by * Sn;
    for (int s = tid; s < Sn; s += 256)
        if (idrow[s] == MASK_ID) lm = min(lm, s);
    #pragma unroll
    for (int m = 32; m; m >>= 1) lm = min(lm, __shfl_xor(lm, m));
    if (l == 0) t4[wv] = lm;
    __syncthreads();
    int mp = min(min(t4[0], t4[1]), min(t4[2], t4[3]));
    if (mp == Sn) mp = 0;

    // ---- q row -> bf16 LDS (once) ----
    {
        float4 v = ((const float4*)(q + ((size_t)by * Sn + mp) * Hn))[tid];
        ((ushort4*)qs)[tid] = make_ushort4(f2bf(v.x), f2bf(v.y), f2bf(v.z), f2bf(v.w));
    }

    // ---- staging geometry: lane -> row (tid>>3 within 32-row group), 16B chunk (tid&7)
    // LDS dest linear; GLOBAL source chunk pre-swizzled by row&7 (both-sides involution)
    const int srow = tid >> 3;                      // 0..31
    const int schk = ((tid & 7) ^ (srow & 7)) * 4;  // f32 element offset of 16B chunk
    const float* aPtr[4];
    #pragma unroll
    for (int j = 0; j < 4; ++j)
        aPtr[j] = seq + ((size_t)by * Sn + (size_t)offs[j * 32 + srow]) * Hn + schk;
    const float* bPtr = W + (size_t)(cbase + srow) * Hn + schk;
    char* AsB = (char*)As;
    char* BsB = (char*)Bs;
    char* qsB = (char*)qs;

    float bv0 = bias[cbase + l15];
    float bv1 = bias[cbase + 16 + l15];

    f32x4 acc00 = {0,0,0,0}, acc01 = {0,0,0,0}, acc10 = {0,0,0,0}, acc11 = {0,0,0,0};
    f32x4 xacc = {0,0,0,0};

    #define STAGE(buf, ks_) do { \
        _Pragma("unroll") \
        for (int j = 0; j < 4; ++j) \
            gload16(aPtr[j] + (ks_) * 32, AsB + (buf) * 16384 + j * 4096 + wv * 1024); \
        gload16(bPtr + (ks_) * 32, BsB + (buf) * 4096 + wv * 1024); \
    } while (0)

    STAGE(0, 0);
    __syncthreads();
    const int sxor = l & 7;                  // row&7 for all this lane's fragment rows
    for (int ks = 0; ks < 32; ++ks) {
        int cur = ks & 1;
        if (ks < 31) STAGE(cur ^ 1, ks + 1);     // async, drains at the barrier below
        const char* Ab = AsB + cur * 16384;
        const char* Bb = BsB + cur * 4096;
        short8 bf0 = ld_cvt(Bb + l15 * 128, sxor, kgrp);
        short8 bf1 = ld_cvt(Bb + (16 + l15) * 128, sxor, kgrp);
        short8 af0 = ld_cvt(Ab + (wv * 32 + l15) * 128, sxor, kgrp);
        short8 af1 = ld_cvt(Ab + (wv * 32 + 16 + l15) * 128, sxor, kgrp);
        acc00 = __builtin_amdgcn_mfma_f32_16x16x32_bf16(af0, bf0, acc00, 0, 0, 0);
        acc01 = __builtin_amdgcn_mfma_f32_16x16x32_bf16(af0, bf1, acc01, 0, 0, 0);
        acc10 = __builtin_amdgcn_mfma_f32_16x16x32_bf16(af1, bf0, acc10, 0, 0, 0);
        acc11 = __builtin_amdgcn_mfma_f32_16x16x32_bf16(af1, bf1, acc11, 0, 0, 0);
        if (wv >= 2) {
            short8 aq = *(const short8*)(qsB + ks * 64 + kgrp * 16);
            xacc = __builtin_amdgcn_mfma_f32_16x16x32_bf16(aq, (wv == 2) ? bf0 : bf1, xacc, 0, 0, 0);
        }
        __syncthreads();
    }
    #undef STAGE

    // ---- x publish (waves 2,3) ----
    if (wv >= 2) {
        float xv = xacc[0] + ((wv == 2) ? bv0 : bv1);
        if (l < 16) xvs[(wv - 2) * 16 + l] = xv;
        float px = xv * xv;
        #pragma unroll
        for (int m = 1; m < 16; m <<= 1) px += __shfl_xor(px, m);
        if (l == 0) xred[wv - 2] = px;
    }
    __syncthreads();

    // ---- per-row partial ||y||^2, x.y over this block's 32 cols ----
    float xv0 = xvs[l15];
    float xv1 = xvs[16 + l15];
    #pragma unroll
    for (int mf = 0; mf < 2; ++mf) {
        f32x4 a0 = mf ? acc10 : acc00;
        f32x4 a1 = mf ? acc11 : acc01;
        #pragma unroll
        for (int reg = 0; reg < 4; ++reg) {
            float y0 = a0[reg] + bv0;
            float y1 = a1[reg] + bv1;
            float y2v = y0 * y0 + y1 * y1;
            float xyv = xv0 * y0 + xv1 * y1;
            #pragma unroll
            for (int m = 1; m < 16; m <<= 1) {
                y2v += __shfl_xor(y2v, m);
                xyv += __shfl_xor(xyv, m);
            }
            if ((l & 15) == 0) {
                int lrow = wv * 32 + mf * 16 + (l >> 4) * 4 + reg;
                red[lrow][0] = y2v;
                red[lrow][1] = xyv;
            }
        }
    }
    __syncthreads();
    if (tid < 128) st_agent(&yn2p[bx * 2048 + rbase + tid], red[tid][0]);
    else           st_agent(&dotp[bx * 2048 + rbase + tid - 128], red[tid - 128][1]);
    if (tid == 0)  st_agent(&xn2p[bx * 16 + by], xred[0] + xred[1]);

    // ---- last-block-done (mod-512: correct for ANY initial counter value) ----
    __threadfence();
    if (tid == 0) {
        unsigned int old = atomicAdd(done, 1u);
        lastf = ((old & 511u) == 511u) ? 1 : 0;
    }
    __syncthreads();
    if (!lastf) return;
    __threadfence();

    // ---- finalize (one block) ----
    if (tid < 16) {
        float s = 0.f;
        #pragma unroll
        for (int b2 = 0; b2 < 32; ++b2) s += ld_agent(&xn2p[b2 * 16 + tid]);
        xns[tid] = sqrtf(s);
        numL[tid] = 0.f;
        denL[tid] = 0.f;
    }
    __syncthreads();
    #pragma unroll
    for (int r8 = 0; r8 < 8; ++r8) {
        int row = r8 * 256 + tid;
        float y2 = 0.f, dt = 0.f;
        #pragma unroll
        for (int b2 = 0; b2 < 32; ++b2) {
            y2 += ld_agent(&yn2p[b2 * 2048 + row]);
            dt += ld_agent(&dotp[b2 * 2048 + row]);
        }
        int b = row >> 7;                       // uniform per wave (64 rows, same batch)
        float c = dt / fmaxf(xns[b] * sqrtf(y2), 1e-8f);
        float e = expf(c);
        float numt = e * (float)labels[row];
        float dent = e * (float)events[row];
        #pragma unroll
        for (int m = 32; m; m >>= 1) { numt += __shfl_xor(numt, m); dent += __shfl_xor(dent, m); }
        if (l == 0) { atomicAdd(&numL[b], numt); atomicAdd(&denL[b], dent); }
    }
    __syncthreads();
    if (tid < 16) ln16[tid] = logf(denL[tid]) - logf(numL[tid]);
    __syncthreads();
    if (wv == 0) {
        float v = (l < 16) ? ln16[l] : 0.f;
        #pragma unroll
        for (int m = 32; m; m >>= 1) v += __shfl_xor(v, m);
        if (l == 0) out[0] = v * (1.0f / Bn);
    }
}

extern "C" void kernel_launch(void* const* d_in, const int* in_sizes, int n_in,
                              void* d_out, int out_size, void* d_ws, size_t ws_size,
                              hipStream_t stream) {
    const int*   input_ids = (const int*)d_in[0];
    const float* q         = (const float*)d_in[1];
    const float* seq       = (const float*)d_in[2];
    const int*   events    = (const int*)d_in[3];
    const int*   labels    = (const int*)d_in[4];
    const int*   offsets   = (const int*)d_in[5];
    const float* W         = (const float*)d_in[7];
    const float* bias      = (const float*)d_in[8];
    float* out = (float*)d_out;

    char* ws = (char*)d_ws;
    float*        yn2p = (float*)(ws);              // 256 KB [32][2048]
    float*        dotp = (float*)(ws + 262144);     // 256 KB [32][2048]
    float*        xn2p = (float*)(ws + 524288);     //   2 KB [32][16]
    unsigned int* done = (unsigned int*)(ws + 526336);

    fused2_k<<<512, 256, 0, stream>>>(input_ids, q, seq, offsets, W, bias,
                                      labels, events, yn2p, dotp, xn2p, done, out);
}

// Round 7
// 67.536 us; speedup vs baseline: 1.4404x; 1.4404x over previous
//
#include <hip/hip_runtime.h>
#include <hip/hip_bf16.h>

#define MASK_ID 50264
#define Bn 16
#define Sn 2048
#define Hn 1024
#define Ln 128

typedef __attribute__((ext_vector_type(8))) short short8;
typedef __attribute__((ext_vector_type(4))) float f32x4;

__device__ __forceinline__ unsigned short f2bf(float f) {
    __hip_bfloat16 h = __float2bfloat16(f);
    return __builtin_bit_cast(unsigned short, h);
}
__device__ __forceinline__ void gload16(const void* g, void* l) {
    __builtin_amdgcn_global_load_lds((const __attribute__((address_space(1))) void*)g,
                                     (__attribute__((address_space(3))) void*)l, 16, 0, 0);
}
__device__ __forceinline__ void st_agent(float* p, float v) {
    __hip_atomic_store(p, v, __ATOMIC_RELAXED, __HIP_MEMORY_SCOPE_AGENT);
}
__device__ __forceinline__ float ld_agent(const float* p) {
    return __hip_atomic_load(p, __ATOMIC_RELAXED, __HIP_MEMORY_SCOPE_AGENT);
}
// read 8 f32 (two XOR-swizzled 16B chunks) from LDS row, convert to bf16 short8
__device__ __forceinline__ short8 ld_cvt(const char* rowbase, int s, int kgrp) {
    f32x4 lo = *(const f32x4*)(rowbase + (((kgrp * 2)     ^ s) << 4));
    f32x4 hi = *(const f32x4*)(rowbase + (((kgrp * 2 + 1) ^ s) << 4));
    short8 r;
    r[0] = (short)f2bf(lo[0]); r[1] = (short)f2bf(lo[1]);
    r[2] = (short)f2bf(lo[2]); r[3] = (short)f2bf(lo[3]);
    r[4] = (short)f2bf(hi[0]); r[5] = (short)f2bf(hi[1]);
    r[6] = (short)f2bf(hi[2]); r[7] = (short)f2bf(hi[3]);
    return r;
}

// ONE kernel, ONE graph node. 512 blocks (16 by x 32 bx), 256 threads (4 waves).
// NO __threadfence (L2-writeback killer): cross-XCD visibility via agent-scope
// atomic stores/loads only; ordering via ACQ_REL on the done counter.
__global__ __launch_bounds__(256, 2) void fused3_k(
        const int* __restrict__ ids, const float* __restrict__ q,
        const float* __restrict__ seq, const int* __restrict__ offsets,
        const float* __restrict__ W, const float* __restrict__ bias,
        const int* __restrict__ labels, const int* __restrict__ events,
        float* __restrict__ yn2p, float* __restrict__ dotp, float* __restrict__ xn2p,
        unsigned int* __restrict__ done, float* __restrict__ out)
{
    __shared__ float As[2][4096];            // 2 x 16KB : [128 rows][32 f32], 16B-chunk XOR swz
    __shared__ float Bs[2][1024];            // 2 x 4KB  : [32 rows][32 f32], same swz
    __shared__ unsigned short qs[1024];      // 2KB bf16, linear
    __shared__ int   offs[128];
    __shared__ int   t4[4];
    __shared__ float xvs[32], xred[2];
    __shared__ float red[128][2];
    __shared__ int   lastf;
    __shared__ float xns[16], numL[16], denL[16], ln16[16];

    const int blk = blockIdx.x, tid = threadIdx.x;
    const int wv = tid >> 6, l = tid & 63;
    // XCD partition: XCD x gets 4 by x 16 bx (L2-friendly)
    const int x = blk & 7, ib = blk >> 3;
    const int by = (x >> 1) * 4 + (ib >> 4);
    const int bx = (x & 1) * 16 + (ib & 15);
    const int rbase = by * 128, cbase = bx * 32;
    const int l15 = l & 15, kgrp = l >> 4;

    if (tid < 128) offs[tid] = offsets[tid];

    // ---- maskpos for this block's batch ----
    int lm = Sn;
    const int* idrow = ids + by * Sn;
    for (int s = tid; s < Sn; s += 256)
        if (idrow[s] == MASK_ID) lm = min(lm, s);
    #pragma unroll
    for (int m = 32; m; m >>= 1) lm = min(lm, __shfl_xor(lm, m));
    if (l == 0) t4[wv] = lm;
    __syncthreads();
    int mp = min(min(t4[0], t4[1]), min(t4[2], t4[3]));
    if (mp == Sn) mp = 0;

    // ---- q row -> bf16 LDS (once) ----
    {
        float4 v = ((const float4*)(q + ((size_t)by * Sn + mp) * Hn))[tid];
        ((ushort4*)qs)[tid] = make_ushort4(f2bf(v.x), f2bf(v.y), f2bf(v.z), f2bf(v.w));
    }

    // ---- staging geometry: lane -> row (tid>>3 within 32-row group), 16B chunk (tid&7)
    // LDS dest linear; GLOBAL source chunk pre-swizzled by row&7 (both-sides involution)
    const int srow = tid >> 3;                      // 0..31
    const int schk = ((tid & 7) ^ (srow & 7)) * 4;  // f32 element offset of 16B chunk
    const float* aPtr[4];
    #pragma unroll
    for (int j = 0; j < 4; ++j)
        aPtr[j] = seq + ((size_t)by * Sn + (size_t)offs[j * 32 + srow]) * Hn + schk;
    const float* bPtr = W + (size_t)(cbase + srow) * Hn + schk;
    char* AsB = (char*)As;
    char* BsB = (char*)Bs;
    char* qsB = (char*)qs;

    float bv0 = bias[cbase + l15];
    float bv1 = bias[cbase + 16 + l15];

    f32x4 acc00 = {0,0,0,0}, acc01 = {0,0,0,0}, acc10 = {0,0,0,0}, acc11 = {0,0,0,0};
    f32x4 xacc = {0,0,0,0};

    #define STAGE(buf, ks_) do { \
        _Pragma("unroll") \
        for (int j = 0; j < 4; ++j) \
            gload16(aPtr[j] + (ks_) * 32, AsB + (buf) * 16384 + j * 4096 + wv * 1024); \
        gload16(bPtr + (ks_) * 32, BsB + (buf) * 4096 + wv * 1024); \
    } while (0)

    STAGE(0, 0);
    __syncthreads();
    const int sxor = l & 7;                  // row&7 for all this lane's fragment rows
    for (int ks = 0; ks < 32; ++ks) {
        int cur = ks & 1;
        if (ks < 31) STAGE(cur ^ 1, ks + 1);     // async, drains at the barrier below
        const char* Ab = AsB + cur * 16384;
        const char* Bb = BsB + cur * 4096;
        short8 bf0 = ld_cvt(Bb + l15 * 128, sxor, kgrp);
        short8 bf1 = ld_cvt(Bb + (16 + l15) * 128, sxor, kgrp);
        short8 af0 = ld_cvt(Ab + (wv * 32 + l15) * 128, sxor, kgrp);
        short8 af1 = ld_cvt(Ab + (wv * 32 + 16 + l15) * 128, sxor, kgrp);
        acc00 = __builtin_amdgcn_mfma_f32_16x16x32_bf16(af0, bf0, acc00, 0, 0, 0);
        acc01 = __builtin_amdgcn_mfma_f32_16x16x32_bf16(af0, bf1, acc01, 0, 0, 0);
        acc10 = __builtin_amdgcn_mfma_f32_16x16x32_bf16(af1, bf0, acc10, 0, 0, 0);
        acc11 = __builtin_amdgcn_mfma_f32_16x16x32_bf16(af1, bf1, acc11, 0, 0, 0);
        if (wv >= 2) {
            short8 aq = *(const short8*)(qsB + ks * 64 + kgrp * 16);
            xacc = __builtin_amdgcn_mfma_f32_16x16x32_bf16(aq, (wv == 2) ? bf0 : bf1, xacc, 0, 0, 0);
        }
        __syncthreads();
    }
    #undef STAGE

    // ---- x publish (waves 2,3) ----
    if (wv >= 2) {
        float xv = xacc[0] + ((wv == 2) ? bv0 : bv1);
        if (l < 16) xvs[(wv - 2) * 16 + l] = xv;
        float px = xv * xv;
        #pragma unroll
        for (int m = 1; m < 16; m <<= 1) px += __shfl_xor(px, m);
        if (l == 0) xred[wv - 2] = px;
    }
    __syncthreads();

    // ---- per-row partial ||y||^2, x.y over this block's 32 cols ----
    float xv0 = xvs[l15];
    float xv1 = xvs[16 + l15];
    #pragma unroll
    for (int mf = 0; mf < 2; ++mf) {
        f32x4 a0 = mf ? acc10 : acc00;
        f32x4 a1 = mf ? acc11 : acc01;
        #pragma unroll
        for (int reg = 0; reg < 4; ++reg) {
            float y0 = a0[reg] + bv0;
            float y1 = a1[reg] + bv1;
            float y2v = y0 * y0 + y1 * y1;
            float xyv = xv0 * y0 + xv1 * y1;
            #pragma unroll
            for (int m = 1; m < 16; m <<= 1) {
                y2v += __shfl_xor(y2v, m);
                xyv += __shfl_xor(xyv, m);
            }
            if ((l & 15) == 0) {
                int lrow = wv * 32 + mf * 16 + (l >> 4) * 4 + reg;
                red[lrow][0] = y2v;
                red[lrow][1] = xyv;
            }
        }
    }
    __syncthreads();
    if (tid < 128) st_agent(&yn2p[bx * 2048 + rbase + tid], red[tid][0]);
    else           st_agent(&dotp[bx * 2048 + rbase + tid - 128], red[tid - 128][1]);
    if (tid == 0)  st_agent(&xn2p[bx * 16 + by], xred[0] + xred[1]);

    // ---- last-block-done: ACQ_REL on the counter orders the agent-scope stores
    // above (release) and the agent-scope loads below (acquire). NO threadfence.
    if (tid == 0) {
        unsigned int old = __hip_atomic_fetch_add(done, 1u, __ATOMIC_ACQ_REL,
                                                  __HIP_MEMORY_SCOPE_AGENT);
        lastf = ((old & 511u) == 511u) ? 1 : 0;
    }
    __syncthreads();
    if (!lastf) return;

    // ---- finalize (one block) ----
    if (tid < 16) {
        float s = 0.f;
        #pragma unroll
        for (int b2 = 0; b2 < 32; ++b2) s += ld_agent(&xn2p[b2 * 16 + tid]);
        xns[tid] = sqrtf(s);
        numL[tid] = 0.f;
        denL[tid] = 0.f;
    }
    __syncthreads();
    #pragma unroll
    for (int r8 = 0; r8 < 8; ++r8) {
        int row = r8 * 256 + tid;
        float y2 = 0.f, dt = 0.f;
        #pragma unroll
        for (int b2 = 0; b2 < 32; ++b2) {
            y2 += ld_agent(&yn2p[b2 * 2048 + row]);
            dt += ld_agent(&dotp[b2 * 2048 + row]);
        }
        int b = row >> 7;                       // uniform per wave (64 rows, same batch)
        float c = dt / fmaxf(xns[b] * sqrtf(y2), 1e-8f);
        float e = expf(c);
        float numt = e * (float)labels[row];
        float dent = e * (float)events[row];
        #pragma unroll
        for (int m = 32; m; m >>= 1) { numt += __shfl_xor(numt, m); dent += __shfl_xor(dent, m); }
        if (l == 0) { atomicAdd(&numL[b], numt); atomicAdd(&denL[b], dent); }
    }
    __syncthreads();
    if (tid < 16) ln16[tid] = logf(denL[tid]) - logf(numL[tid]);
    __syncthreads();
    if (wv == 0) {
        float v = (l < 16) ? ln16[l] : 0.f;
        #pragma unroll
        for (int m = 32; m; m >>= 1) v += __shfl_xor(v, m);
        if (l == 0) out[0] = v * (1.0f / Bn);
    }
}

extern "C" void kernel_launch(void* const* d_in, const int* in_sizes, int n_in,
                              void* d_out, int out_size, void* d_ws, size_t ws_size,
                              hipStream_t stream) {
    const int*   input_ids = (const int*)d_in[0];
    const float* q         = (const float*)d_in[1];
    const float* seq       = (const float*)d_in[2];
    const int*   events    = (const int*)d_in[3];
    const int*   labels    = (const int*)d_in[4];
    const int*   offsets   = (const int*)d_in[5];
    const float* W         = (const float*)d_in[7];
    const float* bias      = (const float*)d_in[8];
    float* out = (float*)d_out;

    char* ws = (char*)d_ws;
    float*        yn2p = (float*)(ws);              // 256 KB [32][2048]
    float*        dotp = (float*)(ws + 262144);     // 256 KB [32][2048]
    float*        xn2p = (float*)(ws + 524288);     //   2 KB [32][16]
    unsigned int* done = (unsigned int*)(ws + 526336);

    fused3_k<<<512, 256, 0, stream>>>(input_ids, q, seq, offsets, W, bias,
                                      labels, events, yn2p, dotp, xn2p, done, out);
}

// Round 8
// 64.439 us; speedup vs baseline: 1.5097x; 1.0481x over previous
//
#include <hip/hip_runtime.h>
#include <hip/hip_bf16.h>

#define MASK_ID 50264
#define Bn 16
#define Sn 2048
#define Hn 1024
#define Ln 128

typedef __attribute__((ext_vector_type(8))) short short8;
typedef __attribute__((ext_vector_type(4))) float f32x4;

__device__ __forceinline__ unsigned short f2bf(float f) {
    __hip_bfloat16 h = __float2bfloat16(f);
    return __builtin_bit_cast(unsigned short, h);
}
__device__ __forceinline__ void gload16(const void* g, void* l) {
    __builtin_amdgcn_global_load_lds((const __attribute__((address_space(1))) void*)g,
                                     (__attribute__((address_space(3))) void*)l, 16, 0, 0);
}
__device__ __forceinline__ void st_agent(float* p, float v) {
    __hip_atomic_store(p, v, __ATOMIC_RELAXED, __HIP_MEMORY_SCOPE_AGENT);
}
__device__ __forceinline__ float ld_agent(const float* p) {
    return __hip_atomic_load(p, __ATOMIC_RELAXED, __HIP_MEMORY_SCOPE_AGENT);
}
// read 8 f32 (two XOR-swizzled 16B chunks) from LDS row, convert to bf16 short8
__device__ __forceinline__ short8 ld_cvt(const char* rowbase, int s, int kgrp) {
    f32x4 lo = *(const f32x4*)(rowbase + (((kgrp * 2)     ^ s) << 4));
    f32x4 hi = *(const f32x4*)(rowbase + (((kgrp * 2 + 1) ^ s) << 4));
    short8 r;
    r[0] = (short)f2bf(lo[0]); r[1] = (short)f2bf(lo[1]);
    r[2] = (short)f2bf(lo[2]); r[3] = (short)f2bf(lo[3]);
    r[4] = (short)f2bf(hi[0]); r[5] = (short)f2bf(hi[1]);
    r[6] = (short)f2bf(hi[2]); r[7] = (short)f2bf(hi[3]);
    return r;
}

// ONE kernel, ONE graph node. 512 blocks (16 by x 32 bx), 256 threads (4 waves).
// K-loop ORDER: ds_read current buffer FIRST, then issue async STAGE of next buffer.
// (STAGE-before-reads forced a conservative vmcnt(0) alias-drain before every
// fragment read -> full memory latency per iteration. Reads-first makes that
// hazard impossible; the staged loads drain once, at the barrier.)
__global__ __launch_bounds__(256, 2) void fused4_k(
        const int* __restrict__ ids, const float* __restrict__ q,
        const float* __restrict__ seq, const int* __restrict__ offsets,
        const float* __restrict__ W, const float* __restrict__ bias,
        const int* __restrict__ labels, const int* __restrict__ events,
        float* __restrict__ yn2p, float* __restrict__ dotp, float* __restrict__ xn2p,
        unsigned int* __restrict__ done, float* __restrict__ out)
{
    __shared__ float As[2][4096];            // 2 x 16KB : [128 rows][32 f32], 16B-chunk XOR swz
    __shared__ float Bs[2][1024];            // 2 x 4KB  : [32 rows][32 f32], same swz
    __shared__ unsigned short qs[1024];      // 2KB bf16, linear
    __shared__ int   offs[128];
    __shared__ int   t4[4];
    __shared__ float xvs[32], xred[2];
    __shared__ float red[128][2];
    __shared__ int   lastf;
    __shared__ float xns[16], numL[16], denL[16], ln16[16];

    const int blk = blockIdx.x, tid = threadIdx.x;
    const int wv = tid >> 6, l = tid & 63;
    // XCD partition: XCD x gets 4 by x 16 bx (L2-friendly)
    const int x = blk & 7, ib = blk >> 3;
    const int by = (x >> 1) * 4 + (ib >> 4);
    const int bx = (x & 1) * 16 + (ib & 15);
    const int rbase = by * 128, cbase = bx * 32;
    const int l15 = l & 15, kgrp = l >> 4;

    if (tid < 128) offs[tid] = offsets[tid];

    // ---- maskpos for this block's batch ----
    int lm = Sn;
    const int* idrow = ids + by * Sn;
    for (int s = tid; s < Sn; s += 256)
        if (idrow[s] == MASK_ID) lm = min(lm, s);
    #pragma unroll
    for (int m = 32; m; m >>= 1) lm = min(lm, __shfl_xor(lm, m));
    if (l == 0) t4[wv] = lm;
    __syncthreads();
    int mp = min(min(t4[0], t4[1]), min(t4[2], t4[3]));
    if (mp == Sn) mp = 0;

    // ---- q row -> bf16 LDS (once) ----
    {
        float4 v = ((const float4*)(q + ((size_t)by * Sn + mp) * Hn))[tid];
        ((ushort4*)qs)[tid] = make_ushort4(f2bf(v.x), f2bf(v.y), f2bf(v.z), f2bf(v.w));
    }

    // ---- staging geometry: lane -> row (tid>>3 within 32-row group), 16B chunk (tid&7)
    // LDS dest linear; GLOBAL source chunk pre-swizzled by row&7 (both-sides involution)
    const int srow = tid >> 3;                      // 0..31
    const int schk = ((tid & 7) ^ (srow & 7)) * 4;  // f32 element offset of 16B chunk
    const float* aPtr[4];
    #pragma unroll
    for (int j = 0; j < 4; ++j)
        aPtr[j] = seq + ((size_t)by * Sn + (size_t)offs[j * 32 + srow]) * Hn + schk;
    const float* bPtr = W + (size_t)(cbase + srow) * Hn + schk;
    char* AsB = (char*)As;
    char* BsB = (char*)Bs;
    char* qsB = (char*)qs;

    float bv0 = bias[cbase + l15];
    float bv1 = bias[cbase + 16 + l15];

    f32x4 acc00 = {0,0,0,0}, acc01 = {0,0,0,0}, acc10 = {0,0,0,0}, acc11 = {0,0,0,0};
    f32x4 xacc = {0,0,0,0};

    #define STAGE(buf, ks_) do { \
        _Pragma("unroll") \
        for (int j = 0; j < 4; ++j) \
            gload16(aPtr[j] + (ks_) * 32, AsB + (buf) * 16384 + j * 4096 + wv * 1024); \
        gload16(bPtr + (ks_) * 32, BsB + (buf) * 4096 + wv * 1024); \
    } while (0)

    STAGE(0, 0);
    __syncthreads();
    const int sxor = l & 7;                  // row&7 for all this lane's fragment rows
    for (int ks = 0; ks < 32; ++ks) {
        int cur = ks & 1;
        const char* Ab = AsB + cur * 16384;
        const char* Bb = BsB + cur * 4096;
        // reads FIRST (no async LDS-writes in flight -> no alias drain possible)
        short8 bf0 = ld_cvt(Bb + l15 * 128, sxor, kgrp);
        short8 bf1 = ld_cvt(Bb + (16 + l15) * 128, sxor, kgrp);
        short8 af0 = ld_cvt(Ab + (wv * 32 + l15) * 128, sxor, kgrp);
        short8 af1 = ld_cvt(Ab + (wv * 32 + 16 + l15) * 128, sxor, kgrp);
        // then issue next-tile async staging (overlaps ds_read drain + MFMA)
        if (ks < 31) STAGE(cur ^ 1, ks + 1);
        acc00 = __builtin_amdgcn_mfma_f32_16x16x32_bf16(af0, bf0, acc00, 0, 0, 0);
        acc01 = __builtin_amdgcn_mfma_f32_16x16x32_bf16(af0, bf1, acc01, 0, 0, 0);
        acc10 = __builtin_amdgcn_mfma_f32_16x16x32_bf16(af1, bf0, acc10, 0, 0, 0);
        acc11 = __builtin_amdgcn_mfma_f32_16x16x32_bf16(af1, bf1, acc11, 0, 0, 0);
        if (wv >= 2) {
            short8 aq = *(const short8*)(qsB + ks * 64 + kgrp * 16);
            xacc = __builtin_amdgcn_mfma_f32_16x16x32_bf16(aq, (wv == 2) ? bf0 : bf1, xacc, 0, 0, 0);
        }
        __syncthreads();
    }
    #undef STAGE

    // ---- x publish (waves 2,3) ----
    if (wv >= 2) {
        float xv = xacc[0] + ((wv == 2) ? bv0 : bv1);
        if (l < 16) xvs[(wv - 2) * 16 + l] = xv;
        float px = xv * xv;
        #pragma unroll
        for (int m = 1; m < 16; m <<= 1) px += __shfl_xor(px, m);
        if (l == 0) xred[wv - 2] = px;
    }
    __syncthreads();

    // ---- per-row partial ||y||^2, x.y over this block's 32 cols ----
    float xv0 = xvs[l15];
    float xv1 = xvs[16 + l15];
    #pragma unroll
    for (int mf = 0; mf < 2; ++mf) {
        f32x4 a0 = mf ? acc10 : acc00;
        f32x4 a1 = mf ? acc11 : acc01;
        #pragma unroll
        for (int reg = 0; reg < 4; ++reg) {
            float y0 = a0[reg] + bv0;
            float y1 = a1[reg] + bv1;
            float y2v = y0 * y0 + y1 * y1;
            float xyv = xv0 * y0 + xv1 * y1;
            #pragma unroll
            for (int m = 1; m < 16; m <<= 1) {
                y2v += __shfl_xor(y2v, m);
                xyv += __shfl_xor(xyv, m);
            }
            if ((l & 15) == 0) {
                int lrow = wv * 32 + mf * 16 + (l >> 4) * 4 + reg;
                red[lrow][0] = y2v;
                red[lrow][1] = xyv;
            }
        }
    }
    __syncthreads();
    if (tid < 128) st_agent(&yn2p[bx * 2048 + rbase + tid], red[tid][0]);
    else           st_agent(&dotp[bx * 2048 + rbase + tid - 128], red[tid - 128][1]);
    if (tid == 0)  st_agent(&xn2p[bx * 16 + by], xred[0] + xred[1]);

    // ---- last-block-done: ACQ_REL orders agent stores (release) / loads (acquire)
    if (tid == 0) {
        unsigned int old = __hip_atomic_fetch_add(done, 1u, __ATOMIC_ACQ_REL,
                                                  __HIP_MEMORY_SCOPE_AGENT);
        lastf = ((old & 511u) == 511u) ? 1 : 0;
    }
    __syncthreads();
    if (!lastf) return;

    // ---- finalize (one block) ----
    if (tid < 16) {
        float s = 0.f;
        #pragma unroll
        for (int b2 = 0; b2 < 32; ++b2) s += ld_agent(&xn2p[b2 * 16 + tid]);
        xns[tid] = sqrtf(s);
        numL[tid] = 0.f;
        denL[tid] = 0.f;
    }
    __syncthreads();
    #pragma unroll
    for (int r8 = 0; r8 < 8; ++r8) {
        int row = r8 * 256 + tid;
        float y2 = 0.f, dt = 0.f;
        #pragma unroll
        for (int b2 = 0; b2 < 32; ++b2) {
            y2 += ld_agent(&yn2p[b2 * 2048 + row]);
            dt += ld_agent(&dotp[b2 * 2048 + row]);
        }
        int b = row >> 7;                       // uniform per wave (64 rows, same batch)
        float c = dt / fmaxf(xns[b] * sqrtf(y2), 1e-8f);
        float e = expf(c);
        float numt = e * (float)labels[row];
        float dent = e * (float)events[row];
        #pragma unroll
        for (int m = 32; m; m >>= 1) { numt += __shfl_xor(numt, m); dent += __shfl_xor(dent, m); }
        if (l == 0) { atomicAdd(&numL[b], numt); atomicAdd(&denL[b], dent); }
    }
    __syncthreads();
    if (tid < 16) ln16[tid] = logf(denL[tid]) - logf(numL[tid]);
    __syncthreads();
    if (wv == 0) {
        float v = (l < 16) ? ln16[l] : 0.f;
        #pragma unroll
        for (int m = 32; m; m >>= 1) v += __shfl_xor(v, m);
        if (l == 0) out[0] = v * (1.0f / Bn);
    }
}

extern "C" void kernel_launch(void* const* d_in, const int* in_sizes, int n_in,
                              void* d_out, int out_size, void* d_ws, size_t ws_size,
                              hipStream_t stream) {
    const int*   input_ids = (const int*)d_in[0];
    const float* q         = (const float*)d_in[1];
    const float* seq       = (const float*)d_in[2];
    const int*   events    = (const int*)d_in[3];
    const int*   labels    = (const int*)d_in[4];
    const int*   offsets   = (const int*)d_in[5];
    const float* W         = (const float*)d_in[7];
    const float* bias      = (const float*)d_in[8];
    float* out = (float*)d_out;

    char* ws = (char*)d_ws;
    float*        yn2p = (float*)(ws);              // 256 KB [32][2048]
    float*        dotp = (float*)(ws + 262144);     // 256 KB [32][2048]
    float*        xn2p = (float*)(ws + 524288);     //   2 KB [32][16]
    unsigned int* done = (unsigned int*)(ws + 526336);

    fused4_k<<<512, 256, 0, stream>>>(input_ids, q, seq, offsets, W, bias,
                                      labels, events, yn2p, dotp, xn2p, done, out);
}

// Round 9
// 50.377 us; speedup vs baseline: 1.9310x; 1.2791x over previous
//
#include <hip/hip_runtime.h>
#include <hip/hip_bf16.h>

#define MASK_ID 50264
#define Bn 16
#define Sn 2048
#define Hn 1024
#define Ln 128

typedef __attribute__((ext_vector_type(8))) short short8;
typedef __attribute__((ext_vector_type(4))) float f32x4;

__device__ __forceinline__ unsigned short f2bf(float f) {
    __hip_bfloat16 h = __float2bfloat16(f);
    return __builtin_bit_cast(unsigned short, h);
}
__device__ __forceinline__ void gload16(const void* g, void* l) {
    __builtin_amdgcn_global_load_lds((const __attribute__((address_space(1))) void*)g,
                                     (__attribute__((address_space(3))) void*)l, 16, 0, 0);
}
// read 8 f32 (two XOR-swizzled 16B chunks) from LDS row, convert to bf16 short8
__device__ __forceinline__ short8 ld_cvt(const char* rowbase, int s, int kgrp) {
    f32x4 lo = *(const f32x4*)(rowbase + (((kgrp * 2)     ^ s) << 4));
    f32x4 hi = *(const f32x4*)(rowbase + (((kgrp * 2 + 1) ^ s) << 4));
    short8 r;
    r[0] = (short)f2bf(lo[0]); r[1] = (short)f2bf(lo[1]);
    r[2] = (short)f2bf(lo[2]); r[3] = (short)f2bf(lo[3]);
    r[4] = (short)f2bf(hi[0]); r[5] = (short)f2bf(hi[1]);
    r[6] = (short)f2bf(hi[2]); r[7] = (short)f2bf(hi[3]);
    return r;
}

// ======== K1: gather + bf16 MFMA GEMM, partials out (PLAIN stores) ========
// 512 blocks (16 by x 32 bx), 256 threads (4 waves). Partials row-major:
// yn2p[row][32], dotp[row][32], xn2p[b][32] so K2 reads contiguously.
__global__ __launch_bounds__(256, 3) void gemm9_k(
        const int* __restrict__ ids, const float* __restrict__ q,
        const float* __restrict__ seq, const int* __restrict__ offsets,
        const float* __restrict__ W, const float* __restrict__ bias,
        float* __restrict__ yn2p, float* __restrict__ dotp, float* __restrict__ xn2p)
{
    __shared__ float As[2][4096];            // 2 x 16KB : [128 rows][32 f32], 16B-chunk XOR swz
    __shared__ float Bs[2][1024];            // 2 x 4KB  : [32 rows][32 f32], same swz
    __shared__ unsigned short qs[1024];      // 2KB bf16, linear
    __shared__ int   offs[128];
    __shared__ int   t4[4];
    __shared__ float xvs[32], xred[2];
    __shared__ float red[128][2];

    const int blk = blockIdx.x, tid = threadIdx.x;
    const int wv = tid >> 6, l = tid & 63;
    // XCD partition: XCD x gets 4 by x 16 bx (L2-friendly)
    const int x = blk & 7, ib = blk >> 3;
    const int by = (x >> 1) * 4 + (ib >> 4);
    const int bx = (x & 1) * 16 + (ib & 15);
    const int rbase = by * 128, cbase = bx * 32;
    const int l15 = l & 15, kgrp = l >> 4;

    if (tid < 128) offs[tid] = offsets[tid];

    // ---- maskpos for this block's batch ----
    int lm = Sn;
    const int* idrow = ids + by * Sn;
    for (int s = tid; s < Sn; s += 256)
        if (idrow[s] == MASK_ID) lm = min(lm, s);
    #pragma unroll
    for (int m = 32; m; m >>= 1) lm = min(lm, __shfl_xor(lm, m));
    if (l == 0) t4[wv] = lm;
    __syncthreads();
    int mp = min(min(t4[0], t4[1]), min(t4[2], t4[3]));
    if (mp == Sn) mp = 0;

    // ---- q row -> bf16 LDS (once) ----
    {
        float4 v = ((const float4*)(q + ((size_t)by * Sn + mp) * Hn))[tid];
        ((ushort4*)qs)[tid] = make_ushort4(f2bf(v.x), f2bf(v.y), f2bf(v.z), f2bf(v.w));
    }

    // ---- staging: lane -> row (tid>>3 in 32-row group), 16B chunk (tid&7)
    // LDS dest linear; GLOBAL source chunk pre-swizzled by row&7 (involution)
    const int srow = tid >> 3;                      // 0..31
    const int schk = ((tid & 7) ^ (srow & 7)) * 4;  // f32 elem offset of 16B chunk
    const float* aPtr[4];
    #pragma unroll
    for (int j = 0; j < 4; ++j)
        aPtr[j] = seq + ((size_t)by * Sn + (size_t)offs[j * 32 + srow]) * Hn + schk;
    const float* bPtr = W + (size_t)(cbase + srow) * Hn + schk;
    char* AsB = (char*)As;
    char* BsB = (char*)Bs;
    char* qsB = (char*)qs;

    float bv0 = bias[cbase + l15];
    float bv1 = bias[cbase + 16 + l15];

    f32x4 acc00 = {0,0,0,0}, acc01 = {0,0,0,0}, acc10 = {0,0,0,0}, acc11 = {0,0,0,0};
    f32x4 xacc = {0,0,0,0};

    #define STAGE(buf, ks_) do { \
        _Pragma("unroll") \
        for (int j = 0; j < 4; ++j) \
            gload16(aPtr[j] + (ks_) * 32, AsB + (buf) * 16384 + j * 4096 + wv * 1024); \
        gload16(bPtr + (ks_) * 32, BsB + (buf) * 4096 + wv * 1024); \
    } while (0)

    STAGE(0, 0);
    __syncthreads();
    const int sxor = l & 7;
    for (int ks = 0; ks < 32; ++ks) {
        int cur = ks & 1;
        const char* Ab = AsB + cur * 16384;
        const char* Bb = BsB + cur * 4096;
        short8 bf0 = ld_cvt(Bb + l15 * 128, sxor, kgrp);
        short8 bf1 = ld_cvt(Bb + (16 + l15) * 128, sxor, kgrp);
        short8 af0 = ld_cvt(Ab + (wv * 32 + l15) * 128, sxor, kgrp);
        short8 af1 = ld_cvt(Ab + (wv * 32 + 16 + l15) * 128, sxor, kgrp);
        if (ks < 31) STAGE(cur ^ 1, ks + 1);
        acc00 = __builtin_amdgcn_mfma_f32_16x16x32_bf16(af0, bf0, acc00, 0, 0, 0);
        acc01 = __builtin_amdgcn_mfma_f32_16x16x32_bf16(af0, bf1, acc01, 0, 0, 0);
        acc10 = __builtin_amdgcn_mfma_f32_16x16x32_bf16(af1, bf0, acc10, 0, 0, 0);
        acc11 = __builtin_amdgcn_mfma_f32_16x16x32_bf16(af1, bf1, acc11, 0, 0, 0);
        if (wv >= 2) {
            short8 aq = *(const short8*)(qsB + ks * 64 + kgrp * 16);
            xacc = __builtin_amdgcn_mfma_f32_16x16x32_bf16(aq, (wv == 2) ? bf0 : bf1, xacc, 0, 0, 0);
        }
        __syncthreads();
    }
    #undef STAGE

    // ---- x publish (waves 2,3) ----
    if (wv >= 2) {
        float xv = xacc[0] + ((wv == 2) ? bv0 : bv1);
        if (l < 16) xvs[(wv - 2) * 16 + l] = xv;
        float px = xv * xv;
        #pragma unroll
        for (int m = 1; m < 16; m <<= 1) px += __shfl_xor(px, m);
        if (l == 0) xred[wv - 2] = px;
    }
    __syncthreads();

    // ---- per-row partial ||y||^2, x.y over this block's 32 cols ----
    float xv0 = xvs[l15];
    float xv1 = xvs[16 + l15];
    #pragma unroll
    for (int mf = 0; mf < 2; ++mf) {
        f32x4 a0 = mf ? acc10 : acc00;
        f32x4 a1 = mf ? acc11 : acc01;
        #pragma unroll
        for (int reg = 0; reg < 4; ++reg) {
            float y0 = a0[reg] + bv0;
            float y1 = a1[reg] + bv1;
            float y2v = y0 * y0 + y1 * y1;
            float xyv = xv0 * y0 + xv1 * y1;
            #pragma unroll
            for (int m = 1; m < 16; m <<= 1) {
                y2v += __shfl_xor(y2v, m);
                xyv += __shfl_xor(xyv, m);
            }
            if ((l & 15) == 0) {
                int lrow = wv * 32 + mf * 16 + (l >> 4) * 4 + reg;
                red[lrow][0] = y2v;
                red[lrow][1] = xyv;
            }
        }
    }
    __syncthreads();
    // plain stores, row-major partials (K2 reads contiguously)
    if (tid < 128) yn2p[(rbase + tid) * 32 + bx] = red[tid][0];
    else           dotp[(rbase + tid - 128) * 32 + bx] = red[tid - 128][1];
    if (tid == 0)  xn2p[by * 32 + bx] = xred[0] + xred[1];
}

// ======== K2: finalize (plain vectorized loads; kernel boundary = coherence) ====
__global__ __launch_bounds__(1024) void final9_k(
        const float* __restrict__ yn2p, const float* __restrict__ dotp,
        const float* __restrict__ xn2p,
        const int* __restrict__ labels, const int* __restrict__ events,
        float* __restrict__ out)
{
    __shared__ float xns[16], wn[32], wd[32], ln16[16];
    const int tid = threadIdx.x;
    const int w = tid >> 6, l = tid & 63;

    if (tid < 16) {
        const f32x4* p = (const f32x4*)(xn2p + tid * 32);
        f32x4 s4 = {0,0,0,0};
        #pragma unroll
        for (int i = 0; i < 8; ++i) s4 += p[i];
        xns[tid] = sqrtf(s4[0] + s4[1] + s4[2] + s4[3]);
    }
    __syncthreads();

    #pragma unroll
    for (int h = 0; h < 2; ++h) {
        int row = h * 1024 + tid;
        const f32x4* py = (const f32x4*)(yn2p + (size_t)row * 32);
        const f32x4* pd = (const f32x4*)(dotp + (size_t)row * 32);
        f32x4 sy = {0,0,0,0}, sd = {0,0,0,0};
        #pragma unroll
        for (int i = 0; i < 8; ++i) { sy += py[i]; sd += pd[i]; }
        float y2 = sy[0] + sy[1] + sy[2] + sy[3];
        float dt = sd[0] + sd[1] + sd[2] + sd[3];
        int b = row >> 7;                        // uniform per wave
        float c = dt / fmaxf(xns[b] * sqrtf(y2), 1e-8f);
        float e = expf(c);
        float numt = e * (float)labels[row];
        float dent = e * (float)events[row];
        #pragma unroll
        for (int m = 32; m; m >>= 1) { numt += __shfl_xor(numt, m); dent += __shfl_xor(dent, m); }
        if (l == 0) { wn[h * 16 + w] = numt; wd[h * 16 + w] = dent; }
    }
    __syncthreads();
    if (tid < 16) {
        int s0 = (tid >> 3) * 16 + (tid & 7) * 2;
        float num = wn[s0] + wn[s0 + 1];
        float den = wd[s0] + wd[s0 + 1];
        ln16[tid] = logf(den) - logf(num);
    }
    __syncthreads();
    if (w == 0) {
        float v = (l < 16) ? ln16[l] : 0.f;
        #pragma unroll
        for (int m = 32; m; m >>= 1) v += __shfl_xor(v, m);
        if (l == 0) out[0] = v * (1.0f / Bn);
    }
}

extern "C" void kernel_launch(void* const* d_in, const int* in_sizes, int n_in,
                              void* d_out, int out_size, void* d_ws, size_t ws_size,
                              hipStream_t stream) {
    const int*   input_ids = (const int*)d_in[0];
    const float* q         = (const float*)d_in[1];
    const float* seq       = (const float*)d_in[2];
    const int*   events    = (const int*)d_in[3];
    const int*   labels    = (const int*)d_in[4];
    const int*   offsets   = (const int*)d_in[5];
    const float* W         = (const float*)d_in[7];
    const float* bias      = (const float*)d_in[8];
    float* out = (float*)d_out;

    char* ws = (char*)d_ws;
    float* yn2p = (float*)(ws);              // 256 KB [2048][32]
    float* dotp = (float*)(ws + 262144);     // 256 KB [2048][32]
    float* xn2p = (float*)(ws + 524288);     //   2 KB [16][32]

    gemm9_k <<<512, 256, 0, stream>>>(input_ids, q, seq, offsets, W, bias,
                                      yn2p, dotp, xn2p);
    final9_k<<<1, 1024, 0, stream>>>(yn2p, dotp, xn2p, labels, events, out);
}

// Round 10
// 36.227 us; speedup vs baseline: 2.6853x; 1.3906x over previous
//
#include <hip/hip_runtime.h>
#include <hip/hip_bf16.h>

#define MASK_ID 50264
#define Bn 16
#define Sn 2048
#define Hn 1024
#define Ln 128

typedef __attribute__((ext_vector_type(8))) short short8;
typedef __attribute__((ext_vector_type(4))) float f32x4;

__device__ __forceinline__ unsigned short f2bf(float f) {
    __hip_bfloat16 h = __float2bfloat16(f);
    return __builtin_bit_cast(unsigned short, h);
}

// ======== K1: pack operands into MFMA-native fragment order ========
// Apk/Wpk chunk c (0..2047) of a 16-row group: ks=c>>6, kgrp=(c>>4)&3, l15=c&15.
// GEMM lane l=kgrp*16+l15 reads byte l*16 of block (group, ks) -> coalesced 1KB.
// blocks 0..127: A (by=blk>>3, rg=blk&7, rows = seq[by, offsets[rg*16+l15], :])
// blocks 128..191: W (cg=blk-128, rows = W[cg*16+l15, :])
// blocks 192..207: q (b=blk-192: maskpos scan + bf16 pack, linear)
__global__ __launch_bounds__(256) void pack_k(
        const int* __restrict__ ids, const float* __restrict__ q,
        const float* __restrict__ seq, const int* __restrict__ offsets,
        const float* __restrict__ W,
        unsigned short* __restrict__ Apk, unsigned short* __restrict__ Wpk,
        unsigned short* __restrict__ Qpk) {
    const int blk = blockIdx.x, tid = threadIdx.x;
    if (blk < 192) {
        const float* src;
        unsigned short* dst;
        if (blk < 128) {
            int by = blk >> 3, rg = blk & 7;
            src = seq + ((size_t)by * Sn + (size_t)offsets[rg * 16 + (tid & 15)]) * Hn;
            dst = Apk + (size_t)blk * 16384;
        } else {
            int cg = blk - 128;
            src = W + (size_t)(cg * 16 + (tid & 15)) * Hn;
            dst = Wpk + (size_t)cg * 16384;
        }
        #pragma unroll
        for (int i = 0; i < 8; ++i) {
            int c = i * 256 + tid;
            int koff = (c >> 4) * 8;
            float4 v0 = *(const float4*)(src + koff);
            float4 v1 = *(const float4*)(src + koff + 4);
            short8 o;
            o[0] = (short)f2bf(v0.x); o[1] = (short)f2bf(v0.y);
            o[2] = (short)f2bf(v0.z); o[3] = (short)f2bf(v0.w);
            o[4] = (short)f2bf(v1.x); o[5] = (short)f2bf(v1.y);
            o[6] = (short)f2bf(v1.z); o[7] = (short)f2bf(v1.w);
            *(short8*)(dst + (size_t)c * 8) = o;
        }
    } else {
        __shared__ int t4[4];
        int b = blk - 192;
        int lm = Sn;
        const int* idrow = ids + b * Sn;
        for (int s = tid; s < Sn; s += 256)
            if (idrow[s] == MASK_ID) lm = min(lm, s);
        #pragma unroll
        for (int m = 32; m; m >>= 1) lm = min(lm, __shfl_xor(lm, m));
        if ((tid & 63) == 0) t4[tid >> 6] = lm;
        __syncthreads();
        int mp = min(min(t4[0], t4[1]), min(t4[2], t4[3]));
        if (mp == Sn) mp = 0;
        float4 v = ((const float4*)(q + ((size_t)b * Sn + mp) * Hn))[tid];
        ((ushort4*)(Qpk + b * Hn))[tid] =
            make_ushort4(f2bf(v.x), f2bf(v.y), f2bf(v.z), f2bf(v.w));
    }
}

// ======== K2: barrier-free MFMA GEMM, 128x64 tiles, no LDS in K-loop ========
// 256 blocks (16 by x 16 bx, XCD-grouped), 4 waves; wave = 32 rows x 64 cols.
// Per K-step per wave: 6 coalesced dwordx4 loads + 1 broadcast + 9 MFMA.
__global__ __launch_bounds__(256, 2) void gemm10_k(
        const unsigned short* __restrict__ Apk, const unsigned short* __restrict__ Wpk,
        const unsigned short* __restrict__ Qpk, const float* __restrict__ bias,
        float* __restrict__ yn2p, float* __restrict__ dotp, float* __restrict__ xn2p) {
    __shared__ float xvs[64];
    __shared__ float xred[4];
    __shared__ float red[128][2];

    const int blk = blockIdx.x, tid = threadIdx.x;
    const int wv = tid >> 6, l = tid & 63;
    // XCD partition: XCD x gets 4 by x 8 bx
    const int x = blk & 7, ib = blk >> 3;            // ib 0..31
    const int by = (x >> 1) * 4 + (ib >> 3);         // 0..15
    const int bx = (x & 1) * 8 + (ib & 7);           // 0..15
    const int rbase = by * 128, cbase = bx * 64;
    const int l15 = l & 15;

    const char* aP0 = (const char*)Apk + ((size_t)((by * 8 + wv * 2) * 32) << 10) + (l << 4);
    const char* aP1 = aP0 + (32 << 10);
    const char* bP  = (const char*)Wpk + ((size_t)(bx * 4 * 32) << 10) + (l << 4);
    const char* qP  = (const char*)Qpk + (by << 11) + ((l >> 4) << 4);

    f32x4 acc[2][4];
    #pragma unroll
    for (int i = 0; i < 2; ++i)
        #pragma unroll
        for (int j = 0; j < 4; ++j) acc[i][j] = (f32x4){0.f, 0.f, 0.f, 0.f};
    f32x4 xacc = {0.f, 0.f, 0.f, 0.f};

    #pragma unroll 2
    for (int ks = 0; ks < 32; ++ks) {
        short8 a0 = *(const short8*)(aP0 + ks * 1024);
        short8 a1 = *(const short8*)(aP1 + ks * 1024);
        short8 b0 = *(const short8*)(bP + ks * 1024);
        short8 b1 = *(const short8*)(bP + ks * 1024 + 32768);
        short8 b2 = *(const short8*)(bP + ks * 1024 + 65536);
        short8 b3 = *(const short8*)(bP + ks * 1024 + 98304);
        short8 aq = *(const short8*)(qP + ks * 64);
        acc[0][0] = __builtin_amdgcn_mfma_f32_16x16x32_bf16(a0, b0, acc[0][0], 0, 0, 0);
        acc[0][1] = __builtin_amdgcn_mfma_f32_16x16x32_bf16(a0, b1, acc[0][1], 0, 0, 0);
        acc[0][2] = __builtin_amdgcn_mfma_f32_16x16x32_bf16(a0, b2, acc[0][2], 0, 0, 0);
        acc[0][3] = __builtin_amdgcn_mfma_f32_16x16x32_bf16(a0, b3, acc[0][3], 0, 0, 0);
        acc[1][0] = __builtin_amdgcn_mfma_f32_16x16x32_bf16(a1, b0, acc[1][0], 0, 0, 0);
        acc[1][1] = __builtin_amdgcn_mfma_f32_16x16x32_bf16(a1, b1, acc[1][1], 0, 0, 0);
        acc[1][2] = __builtin_amdgcn_mfma_f32_16x16x32_bf16(a1, b2, acc[1][2], 0, 0, 0);
        acc[1][3] = __builtin_amdgcn_mfma_f32_16x16x32_bf16(a1, b3, acc[1][3], 0, 0, 0);
        short8 bw = (wv == 0) ? b0 : (wv == 1) ? b1 : (wv == 2) ? b2 : b3;
        xacc = __builtin_amdgcn_mfma_f32_16x16x32_bf16(aq, bw, xacc, 0, 0, 0);
    }

    // ---- x publish: wave wv owns cols [wv*16, wv*16+16) of this 64-col panel ----
    float bvx = bias[cbase + wv * 16 + l15];
    float xv_own = xacc[0] + bvx;            // rows of xacc identical; reg0 ok
    if (l < 16) xvs[wv * 16 + l] = xv_own;
    {
        float px = (l < 16) ? xv_own * xv_own : 0.f;
        #pragma unroll
        for (int m = 1; m < 16; m <<= 1) px += __shfl_xor(px, m);
        if (l == 0) xred[wv] = px;
    }
    __syncthreads();

    // ---- per-row partials over this block's 64 cols ----
    float xv[4], bv[4];
    #pragma unroll
    for (int nf = 0; nf < 4; ++nf) {
        xv[nf] = xvs[nf * 16 + l15];
        bv[nf] = bias[cbase + nf * 16 + l15];
    }
    #pragma unroll
    for (int i = 0; i < 2; ++i) {
        #pragma unroll
        for (int reg = 0; reg < 4; ++reg) {
            float y2v = 0.f, xyv = 0.f;
            #pragma unroll
            for (int nf = 0; nf < 4; ++nf) {
                float y = acc[i][nf][reg] + bv[nf];
                y2v += y * y;
                xyv += xv[nf] * y;
            }
            #pragma unroll
            for (int m = 1; m < 16; m <<= 1) {
                y2v += __shfl_xor(y2v, m);
                xyv += __shfl_xor(xyv, m);
            }
            if (l15 == 0) {
                int lrow = wv * 32 + i * 16 + (l >> 4) * 4 + reg;
                red[lrow][0] = y2v;
                red[lrow][1] = xyv;
            }
        }
    }
    __syncthreads();
    if (tid < 128) yn2p[(size_t)(rbase + tid) * 16 + bx] = red[tid][0];
    else           dotp[(size_t)(rbase + tid - 128) * 16 + bx] = red[tid - 128][1];
    if (tid == 0)  xn2p[by * 16 + bx] = xred[0] + xred[1] + xred[2] + xred[3];
}

// ======== K3: finalize (plain vectorized loads) ========
__global__ __launch_bounds__(1024) void final10_k(
        const float* __restrict__ yn2p, const float* __restrict__ dotp,
        const float* __restrict__ xn2p,
        const int* __restrict__ labels, const int* __restrict__ events,
        float* __restrict__ out) {
    __shared__ float xns[16], wn[32], wd[32], ln16[16];
    const int tid = threadIdx.x;
    const int w = tid >> 6, l = tid & 63;

    if (tid < 16) {
        const f32x4* p = (const f32x4*)(xn2p + tid * 16);
        f32x4 s4 = p[0] + p[1] + p[2] + p[3];
        xns[tid] = sqrtf(s4[0] + s4[1] + s4[2] + s4[3]);
    }
    __syncthreads();

    #pragma unroll
    for (int h = 0; h < 2; ++h) {
        int row = h * 1024 + tid;
        const f32x4* py = (const f32x4*)(yn2p + (size_t)row * 16);
        const f32x4* pd = (const f32x4*)(dotp + (size_t)row * 16);
        f32x4 sy = py[0] + py[1] + py[2] + py[3];
        f32x4 sd = pd[0] + pd[1] + pd[2] + pd[3];
        float y2 = sy[0] + sy[1] + sy[2] + sy[3];
        float dt = sd[0] + sd[1] + sd[2] + sd[3];
        int b = row >> 7;                        // uniform per wave
        float c = dt / fmaxf(xns[b] * sqrtf(y2), 1e-8f);
        float e = expf(c);
        float numt = e * (float)labels[row];
        float dent = e * (float)events[row];
        #pragma unroll
        for (int m = 32; m; m >>= 1) { numt += __shfl_xor(numt, m); dent += __shfl_xor(dent, m); }
        if (l == 0) { wn[h * 16 + w] = numt; wd[h * 16 + w] = dent; }
    }
    __syncthreads();
    if (tid < 16) {
        int s0 = (tid >> 3) * 16 + (tid & 7) * 2;
        float num = wn[s0] + wn[s0 + 1];
        float den = wd[s0] + wd[s0 + 1];
        ln16[tid] = logf(den) - logf(num);
    }
    __syncthreads();
    if (w == 0) {
        float v = (l < 16) ? ln16[l] : 0.f;
        #pragma unroll
        for (int m = 32; m; m >>= 1) v += __shfl_xor(v, m);
        if (l == 0) out[0] = v * (1.0f / Bn);
    }
}

extern "C" void kernel_launch(void* const* d_in, const int* in_sizes, int n_in,
                              void* d_out, int out_size, void* d_ws, size_t ws_size,
                              hipStream_t stream) {
    const int*   input_ids = (const int*)d_in[0];
    const float* q         = (const float*)d_in[1];
    const float* seq       = (const float*)d_in[2];
    const int*   events    = (const int*)d_in[3];
    const int*   labels    = (const int*)d_in[4];
    const int*   offsets   = (const int*)d_in[5];
    const float* W         = (const float*)d_in[7];
    const float* bias      = (const float*)d_in[8];
    float* out = (float*)d_out;

    char* ws = (char*)d_ws;
    unsigned short* Apk = (unsigned short*)(ws);             // 4 MB
    unsigned short* Wpk = (unsigned short*)(ws + 4194304);   // 2 MB
    unsigned short* Qpk = (unsigned short*)(ws + 6291456);   // 32 KB
    float* yn2p = (float*)(ws + 6324224);                    // 128 KB [2048][16]
    float* dotp = (float*)(ws + 6455296);                    // 128 KB [2048][16]
    float* xn2p = (float*)(ws + 6586368);                    //   1 KB [16][16]

    pack_k  <<<208, 256, 0, stream>>>(input_ids, q, seq, offsets, W, Apk, Wpk, Qpk);
    gemm10_k<<<256, 256, 0, stream>>>(Apk, Wpk, Qpk, bias, yn2p, dotp, xn2p);
    final10_k<<<1, 1024, 0, stream>>>(yn2p, dotp, xn2p, labels, events, out);
}